// Round 7
// baseline (141.547 us; speedup 1.0000x reference)
//
#include <hip/hip_runtime.h>

// Shapes (fixed): x (32,12,256,256) f32, weight (256,12,1,1) f32, bias (256) f32
// Outputs: t (32,12,128,128) then out (32,256,128,128), concatenated in d_out.

#define T_ELEMS 6291456      // 32*12*128*128
#define HW_T    16384        // 128*128
#define HW_X    65536        // 256*256

typedef float f2v __attribute__((ext_vector_type(2)));

// Fully fused: iwt(up2)->blur(down2)->dwt(down2) as one separable stride-2
// 4x4-tap filter bank (t kept in registers, nt-stored), then 12->256 1x1
// conv + bias + lrelu*sqrt2 directly from registers.
// 2 px/thread: block = 256 threads = 4 waves = 4 u-rows (64 lanes x 2 px).
// Grid (32, 32) = 1024 blocks -> 16 waves/CU.
// R7 = R4 with ONE change: out-stores are plain (not nt). Lockstep oo walk
// (R5 showed stagger regresses hard); predicated edge loads (R6 showed shfl
// halo is worse).
__global__ __launch_bounds__(256) void fused_fromrgb_kernel(
    const float* __restrict__ x, const float* __restrict__ w,
    const float* __restrict__ bias, float* __restrict__ t,
    float* __restrict__ out)
{
    __shared__ float ws[256 * 12];
    __shared__ float bs[256];
    const int tid = threadIdx.x;

    // Stage weights (overlaps with phase 1; sync deferred until conv).
    const float wscale = 0.2886751345948129f;   // 1/sqrt(12)
    bs[tid] = bias[tid];
    #pragma unroll
    for (int i = 0; i < 12; ++i)
        ws[i * 256 + tid] = w[i * 256 + tid] * wscale;  // flat fill of ws[oo*12+c]

    const int l  = tid & 63;                  // lane: v = 2l, 2l+1
    const int ur = tid >> 6;                  // 0..3
    const int u  = blockIdx.x * 4 + ur;       // 0..127
    const int b  = blockIdx.y;                // 0..31

    const float F[2][2][4] = {
        { { 1.f,  7.f,  7.f,  1.f}, {-1.f, -1.f, 1.f,  1.f} },  // analysis L
        { { 1.f,  5.f, -5.f, -1.f}, {-1.f,  1.f, 1.f, -1.f} }   // analysis H
    };

    const int r0    = 2 * u - 1;
    const int cbase = 4 * l;                  // cols cbase-1 .. cbase+4

    float tv[12][2];                          // t values, kept for the conv

    #pragma unroll
    for (int ch = 0; ch < 3; ++ch) {
        float acc[4][2];                      // [kind ll,lh,hl,hh][px]
        #pragma unroll
        for (int k = 0; k < 4; ++k) { acc[k][0] = 0.f; acc[k][1] = 0.f; }

        #pragma unroll
        for (int g = 0; g < 4; ++g) {         // input groups: ll,-lh,-hl,hh
            const int gr = g & 1, gc = g >> 1;
            const float* xp = x + ((size_t)(b * 12 + g * 3 + ch)) * HW_X;
            #pragma unroll
            for (int dy = 0; dy < 4; ++dy) {
                const int r = r0 + dy;
                float c[6];
                if (r >= 0 && r < 256) {
                    const float* rp = xp + (r << 8) + cbase;
                    const float4 A = *reinterpret_cast<const float4*>(rp);
                    c[1] = A.x; c[2] = A.y; c[3] = A.z; c[4] = A.w;
                    c[0] = (l > 0)  ? rp[-1] : 0.f;
                    c[5] = (l < 63) ? rp[4]  : 0.f;
                } else {
                    #pragma unroll
                    for (int i = 0; i < 6; ++i) c[i] = 0.f;
                }
                #pragma unroll
                for (int p = 0; p < 2; ++p) {
                    float s0 = 0.f, s1 = 0.f;
                    #pragma unroll
                    for (int dx = 0; dx < 4; ++dx) {
                        s0 = fmaf(F[0][gc][dx], c[2 * p + dx], s0);
                        s1 = fmaf(F[1][gc][dx], c[2 * p + dx], s1);
                    }
                    acc[0][p] = fmaf(F[0][gr][dy], s0, acc[0][p]);
                    acc[1][p] = fmaf(F[1][gr][dy], s0, acc[1][p]);
                    acc[2][p] = fmaf(F[0][gr][dy], s1, acc[2][p]);
                    acc[3][p] = fmaf(F[1][gr][dy], s1, acc[3][p]);
                }
            }
        }

        const float sc = 1.f / 256.f;
        #pragma unroll
        for (int k = 0; k < 4; ++k) {
            f2v o;
            o.x = acc[k][0] * sc; o.y = acc[k][1] * sc;
            tv[k * 3 + ch][0] = o.x; tv[k * 3 + ch][1] = o.y;
            __builtin_nontemporal_store(o, reinterpret_cast<f2v*>(
                t + ((size_t)(b * 12 + k * 3 + ch)) * HW_T + (u << 7) + 2 * l));
        }
    }

    __syncthreads();   // ws/bs ready

    // ---- 1x1 conv: 256 output channels from the 12 register-resident t's
    const float SQ2 = 1.4142135623730951f;
    const int base = (u << 7) + 2 * l;
    float* outp = out + ((size_t)b * 256) * HW_T + base;

    #pragma unroll 4
    for (int oo = 0; oo < 256; ++oo) {
        const float4 w0 = *reinterpret_cast<const float4*>(&ws[oo * 12 + 0]);
        const float4 w1 = *reinterpret_cast<const float4*>(&ws[oo * 12 + 4]);
        const float4 w2 = *reinterpret_cast<const float4*>(&ws[oo * 12 + 8]);
        const float bo = bs[oo];
        float a0 = bo, a1 = bo;
        #pragma unroll
        for (int c = 0; c < 4; ++c) {
            const float wv = (&w0.x)[c];
            a0 = fmaf(tv[c][0], wv, a0); a1 = fmaf(tv[c][1], wv, a1);
        }
        #pragma unroll
        for (int c = 0; c < 4; ++c) {
            const float wv = (&w1.x)[c];
            a0 = fmaf(tv[c + 4][0], wv, a0); a1 = fmaf(tv[c + 4][1], wv, a1);
        }
        #pragma unroll
        for (int c = 0; c < 4; ++c) {
            const float wv = (&w2.x)[c];
            a0 = fmaf(tv[c + 8][0], wv, a0); a1 = fmaf(tv[c + 8][1], wv, a1);
        }
        f2v av;
        av.x = fmaxf(a0, 0.2f * a0) * SQ2;
        av.y = fmaxf(a1, 0.2f * a1) * SQ2;
        *reinterpret_cast<f2v*>(outp + (size_t)oo * HW_T) = av;   // plain store
    }
}

extern "C" void kernel_launch(void* const* d_in, const int* in_sizes, int n_in,
                              void* d_out, int out_size, void* d_ws, size_t ws_size,
                              hipStream_t stream) {
    const float* x    = (const float*)d_in[0];
    const float* wgt  = (const float*)d_in[1];
    const float* bias = (const float*)d_in[2];
    float* t   = (float*)d_out;
    float* out = t + T_ELEMS;

    dim3 blk(256, 1, 1), grd(32, 32, 1);
    hipLaunchKernelGGL(fused_fromrgb_kernel, grd, blk, 0, stream,
                       x, wgt, bias, t, out);
}

// Round 8
// 129.515 us; speedup vs baseline: 1.0929x; 1.0929x over previous
//
#include <hip/hip_runtime.h>

// Shapes (fixed): x (32,12,256,256) f32, weight (256,12,1,1) f32, bias (256) f32
// Outputs: t (32,12,128,128) then out (32,256,128,128), concatenated in d_out.

#define T_ELEMS 6291456      // 32*12*128*128
#define HW_T    16384        // 128*128
#define HW_X    65536        // 256*256

typedef float f2v __attribute__((ext_vector_type(2)));

// Fully fused: iwt(up2)->blur(down2)->dwt(down2) as one separable stride-2
// 4x4-tap filter bank (t kept in registers, nt-stored), then 12->256 1x1
// conv + bias + lrelu*sqrt2 directly from registers.
// 2 px/thread: block = 256 threads = 4 waves = 4 u-rows (64 lanes x 2 px).
// Grid (32, 32) = 1024 blocks -> 16 waves/CU.
// R8 = R4 verbatim (best config). Ledger: nt out-stores +8% (R7 ablation),
// lockstep oo walk (R5: stagger -9%), predicated edge loads (R6: shfl -5%),
// 16 waves/CU (R3->R4: +2%).
__global__ __launch_bounds__(256) void fused_fromrgb_kernel(
    const float* __restrict__ x, const float* __restrict__ w,
    const float* __restrict__ bias, float* __restrict__ t,
    float* __restrict__ out)
{
    __shared__ float ws[256 * 12];
    __shared__ float bs[256];
    const int tid = threadIdx.x;

    // Stage weights (overlaps with phase 1; sync deferred until conv).
    const float wscale = 0.2886751345948129f;   // 1/sqrt(12)
    bs[tid] = bias[tid];
    #pragma unroll
    for (int i = 0; i < 12; ++i)
        ws[i * 256 + tid] = w[i * 256 + tid] * wscale;  // flat fill of ws[oo*12+c]

    const int l  = tid & 63;                  // lane: v = 2l, 2l+1
    const int ur = tid >> 6;                  // 0..3
    const int u  = blockIdx.x * 4 + ur;       // 0..127
    const int b  = blockIdx.y;                // 0..31

    const float F[2][2][4] = {
        { { 1.f,  7.f,  7.f,  1.f}, {-1.f, -1.f, 1.f,  1.f} },  // analysis L
        { { 1.f,  5.f, -5.f, -1.f}, {-1.f,  1.f, 1.f, -1.f} }   // analysis H
    };

    const int r0    = 2 * u - 1;
    const int cbase = 4 * l;                  // cols cbase-1 .. cbase+4

    float tv[12][2];                          // t values, kept for the conv

    #pragma unroll
    for (int ch = 0; ch < 3; ++ch) {
        float acc[4][2];                      // [kind ll,lh,hl,hh][px]
        #pragma unroll
        for (int k = 0; k < 4; ++k) { acc[k][0] = 0.f; acc[k][1] = 0.f; }

        #pragma unroll
        for (int g = 0; g < 4; ++g) {         // input groups: ll,-lh,-hl,hh
            const int gr = g & 1, gc = g >> 1;
            const float* xp = x + ((size_t)(b * 12 + g * 3 + ch)) * HW_X;
            #pragma unroll
            for (int dy = 0; dy < 4; ++dy) {
                const int r = r0 + dy;
                float c[6];
                if (r >= 0 && r < 256) {
                    const float* rp = xp + (r << 8) + cbase;
                    const float4 A = *reinterpret_cast<const float4*>(rp);
                    c[1] = A.x; c[2] = A.y; c[3] = A.z; c[4] = A.w;
                    c[0] = (l > 0)  ? rp[-1] : 0.f;
                    c[5] = (l < 63) ? rp[4]  : 0.f;
                } else {
                    #pragma unroll
                    for (int i = 0; i < 6; ++i) c[i] = 0.f;
                }
                #pragma unroll
                for (int p = 0; p < 2; ++p) {
                    float s0 = 0.f, s1 = 0.f;
                    #pragma unroll
                    for (int dx = 0; dx < 4; ++dx) {
                        s0 = fmaf(F[0][gc][dx], c[2 * p + dx], s0);
                        s1 = fmaf(F[1][gc][dx], c[2 * p + dx], s1);
                    }
                    acc[0][p] = fmaf(F[0][gr][dy], s0, acc[0][p]);
                    acc[1][p] = fmaf(F[1][gr][dy], s0, acc[1][p]);
                    acc[2][p] = fmaf(F[0][gr][dy], s1, acc[2][p]);
                    acc[3][p] = fmaf(F[1][gr][dy], s1, acc[3][p]);
                }
            }
        }

        const float sc = 1.f / 256.f;
        #pragma unroll
        for (int k = 0; k < 4; ++k) {
            f2v o;
            o.x = acc[k][0] * sc; o.y = acc[k][1] * sc;
            tv[k * 3 + ch][0] = o.x; tv[k * 3 + ch][1] = o.y;
            __builtin_nontemporal_store(o, reinterpret_cast<f2v*>(
                t + ((size_t)(b * 12 + k * 3 + ch)) * HW_T + (u << 7) + 2 * l));
        }
    }

    __syncthreads();   // ws/bs ready

    // ---- 1x1 conv: 256 output channels from the 12 register-resident t's
    const float SQ2 = 1.4142135623730951f;
    const int base = (u << 7) + 2 * l;
    float* outp = out + ((size_t)b * 256) * HW_T + base;

    #pragma unroll 4
    for (int oo = 0; oo < 256; ++oo) {
        const float4 w0 = *reinterpret_cast<const float4*>(&ws[oo * 12 + 0]);
        const float4 w1 = *reinterpret_cast<const float4*>(&ws[oo * 12 + 4]);
        const float4 w2 = *reinterpret_cast<const float4*>(&ws[oo * 12 + 8]);
        const float bo = bs[oo];
        float a0 = bo, a1 = bo;
        #pragma unroll
        for (int c = 0; c < 4; ++c) {
            const float wv = (&w0.x)[c];
            a0 = fmaf(tv[c][0], wv, a0); a1 = fmaf(tv[c][1], wv, a1);
        }
        #pragma unroll
        for (int c = 0; c < 4; ++c) {
            const float wv = (&w1.x)[c];
            a0 = fmaf(tv[c + 4][0], wv, a0); a1 = fmaf(tv[c + 4][1], wv, a1);
        }
        #pragma unroll
        for (int c = 0; c < 4; ++c) {
            const float wv = (&w2.x)[c];
            a0 = fmaf(tv[c + 8][0], wv, a0); a1 = fmaf(tv[c + 8][1], wv, a1);
        }
        f2v av;
        av.x = fmaxf(a0, 0.2f * a0) * SQ2;
        av.y = fmaxf(a1, 0.2f * a1) * SQ2;
        __builtin_nontemporal_store(
            av, reinterpret_cast<f2v*>(outp + (size_t)oo * HW_T));
    }
}

extern "C" void kernel_launch(void* const* d_in, const int* in_sizes, int n_in,
                              void* d_out, int out_size, void* d_ws, size_t ws_size,
                              hipStream_t stream) {
    const float* x    = (const float*)d_in[0];
    const float* wgt  = (const float*)d_in[1];
    const float* bias = (const float*)d_in[2];
    float* t   = (float*)d_out;
    float* out = t + T_ELEMS;

    dim3 blk(256, 1, 1), grd(32, 32, 1);
    hipLaunchKernelGGL(fused_fromrgb_kernel, grd, blk, 0, stream,
                       x, wgt, bias, t, out);
}